// Round 15
// baseline (372.050 us; speedup 1.0000x reference)
//
#include <hip/hip_runtime.h>
#include <cstdint>
#include <cstddef>

#define E_DIM 512
#define H_DIM 512
#define V_DIM 32000
#define B_DIM 64
#define T_DIM 20
#define NBLK 32        // LSTM blocks (16 units each); blocks 32.. convert+FC
#define NBLK_TOT 256
#define PT_LDS 68      // pT row stride (f32)
#define HS_STR 532     // hS row stride (f16): 266 dw == 10 mod 32 -> 2-way
#define N_TILES 2500   // FC tiles: 10 mt x 250 nt

typedef _Float16 f16;
typedef _Float16 f16x8 __attribute__((ext_vector_type(8)));
typedef _Float16 f16x4 __attribute__((ext_vector_type(4)));
typedef float    f32x4 __attribute__((ext_vector_type(4)));

__device__ __forceinline__ void async_lds16(void* lds, const void* g) {
  __builtin_amdgcn_global_load_lds(
      (const __attribute__((address_space(1))) uint32_t*)g,
      (__attribute__((address_space(3))) uint32_t*)lds, 16, 0, 0);
}

__device__ __forceinline__ float sigmoidf_(float x) {
  return 1.0f / (1.0f + expf(-x));
}

// Agent-coherent (cross-XCD) accesses — bypass non-coherent per-XCD L2s.
__device__ __forceinline__ f16x8 load_h8_coh(const f16* p) {
  union { unsigned long long u[2]; f16x8 v; } r;
  r.u[0] = __hip_atomic_load((const unsigned long long*)p,
                             __ATOMIC_RELAXED, __HIP_MEMORY_SCOPE_AGENT);
  r.u[1] = __hip_atomic_load((const unsigned long long*)(p + 4),
                             __ATOMIC_RELAXED, __HIP_MEMORY_SCOPE_AGENT);
  return r.v;
}
__device__ __forceinline__ void store_h4_coh(f16* p, f16x4 v) {
  union { f16x4 h; unsigned long long u; } cvt;
  cvt.h = v;
  __hip_atomic_store((unsigned long long*)p, cvt.u,
                     __ATOMIC_RELAXED, __HIP_MEMORY_SCOPE_AGENT);
}

// ---------------------------------------------------------------------------
// Gather x rows to fp16, T-MAJOR: x16[m'][512], m' = t*64 + b.
// ---------------------------------------------------------------------------
__global__ __launch_bounds__(128) void gather_x16_kernel(
    const float* __restrict__ features, const int* __restrict__ captions,
    const float* __restrict__ emb, f16* __restrict__ x16) {
  const int m = blockIdx.x;
  const int j = threadIdx.x;
  f16x4 r4 = {(f16)0.f, (f16)0.f, (f16)0.f, (f16)0.f};
  if (m < 1344) {
    const int b = m & 63;
    const int t = m >> 6;
    const float* src = (t == 0)
        ? features + (size_t)b * E_DIM
        : emb + (size_t)captions[b * T_DIM + (t - 1)] * E_DIM;
    const float4 v = ((const float4*)src)[j];
    r4.x = (f16)v.x; r4.y = (f16)v.y; r4.z = (f16)v.z; r4.w = (f16)v.w;
  }
  ((f16x4*)(x16 + (size_t)m * 512))[j] = r4;
}

__global__ __launch_bounds__(256) void convert_w_kernel(
    const float* __restrict__ w, f16* __restrict__ w16) {
  const int i = blockIdx.x * 256 + threadIdx.x;
  const float4 v = ((const float4*)w)[i];
  f16x4 r;
  r.x = (f16)v.x; r.y = (f16)v.y; r.z = (f16)v.z; r.w = (f16)v.w;
  ((f16x4*)w16)[i] = r;
}

__global__ __launch_bounds__(256) void bias_sum_kernel(
    const float* __restrict__ a, const float* __restrict__ b,
    float* __restrict__ o) {
  const int i = blockIdx.x * 256 + threadIdx.x;
  if (i < 2048) o[i] = a[i] + b[i];
}

// ---------------------------------------------------------------------------
// K=512 fp16 GEMM (B^T form). mode 0: plain; mode 1: FC row-remap;
// mode 2: proj P_T write off = (m>>6)*131072 + n*64 + (m&63).
// ---------------------------------------------------------------------------
__global__ __launch_bounds__(256) void gemm16_kernel(
    const f16* __restrict__ A, const f16* __restrict__ Bw,
    const float* __restrict__ bias, float* __restrict__ C, int ldc,
    int mode) {
  __shared__ f16 As[128 * 64];
  __shared__ f16 Bs[128 * 64];
  const int tid = threadIdx.x;
  const int lane = tid & 63;
  const int wid = tid >> 6;
  const int m0 = blockIdx.y * 128;
  const int n0 = blockIdx.x * 128;
  const int wm = (wid >> 1) * 64;
  const int wn = (wid & 1) * 64;

  f32x4 acc[4][4];
#pragma unroll
  for (int i = 0; i < 4; ++i)
#pragma unroll
    for (int j = 0; j < 4; ++j) {
      f32x4 z = {0.f, 0.f, 0.f, 0.f};
      acc[i][j] = z;
    }
  const int lr = lane & 15;
  const int lkb = (lane >> 4) * 8;

  for (int kt = 0; kt < 512; kt += 64) {
#pragma unroll
    for (int i = 0; i < 4; ++i) {
      const int off = i * 4096 + wid * 1024 + lane * 16;
      const int row = off >> 7;
      const int colh = (off & 127) >> 1;
      async_lds16((char*)As + i * 4096 + wid * 1024,
                  A + (size_t)(m0 + row) * 512 + kt + colh);
      async_lds16((char*)Bs + i * 4096 + wid * 1024,
                  Bw + (size_t)(n0 + row) * 512 + kt + colh);
    }
    __syncthreads();
#pragma unroll
    for (int ks = 0; ks < 2; ++ks) {
      f16x8 af[4], bf[4];
#pragma unroll
      for (int mi = 0; mi < 4; ++mi)
        af[mi] = *(const f16x8*)&As[(wm + mi * 16 + lr) * 64 + ks * 32 + lkb];
#pragma unroll
      for (int ni = 0; ni < 4; ++ni)
        bf[ni] = *(const f16x8*)&Bs[(wn + ni * 16 + lr) * 64 + ks * 32 + lkb];
#pragma unroll
      for (int mi = 0; mi < 4; ++mi)
#pragma unroll
        for (int ni = 0; ni < 4; ++ni)
          acc[mi][ni] = __builtin_amdgcn_mfma_f32_16x16x32_f16(
              af[mi], bf[ni], acc[mi][ni], 0, 0, 0);
    }
    __syncthreads();
  }

#pragma unroll
  for (int mi = 0; mi < 4; ++mi) {
    const int mbase = m0 + wm + mi * 16 + (lane >> 4) * 4;
#pragma unroll
    for (int ni = 0; ni < 4; ++ni) {
      const int n = n0 + wn + ni * 16 + lr;
      const float bv = bias[n];
#pragma unroll
      for (int r = 0; r < 4; ++r) {
        const int mr = mbase + r;
        size_t off;
        if (mode == 2)
          off = (size_t)(mr >> 6) * (2048 * 64) + (size_t)n * 64 + (mr & 63);
        else if (mode == 1)
          off = (size_t)((mr & 63) * 20 + (mr >> 6)) * ldc + n;
        else
          off = (size_t)mr * ldc + n;
        C[off] = acc[mi][ni][r] + bv;
      }
    }
  }
}

// ---------------------------------------------------------------------------
// MEGA kernel: blocks 0..31 = 21-step persistent LSTM (publishes flags[t]);
// blocks 32..255 = fc_w f32->f16 convert via COHERENT stores (write-once,
// no dirty L2 lines -> cross-XCD readable), then convDone++.
// Afterwards ALL blocks pull FC tiles (128x128, f16 logits out) from a
// dynamic queue; tile (mt,nt) waits on flags >= 3+2*mt (its two hsT slabs).
// A-tile staged via coherent loads (hsT write-once), B via global_load_lds.
// LDS: hS 68.1K + pT 17.4K + hS2 2K -> 1 block/CU, all 256 co-resident.
// ---------------------------------------------------------------------------
__global__ __launch_bounds__(256, 1) void mega_kernel(
    const float* __restrict__ PT, const f16* __restrict__ Whh,
    f16* __restrict__ hsT, unsigned* __restrict__ flags,
    const float* __restrict__ fcw, f16* __restrict__ w16,
    const float* __restrict__ fcb, f16* __restrict__ logits16,
    unsigned* __restrict__ convDone, unsigned* __restrict__ queue,
    int do_fc) {
  __shared__ f16 hS[64 * HS_STR];         // 68.1 KB (FC: As/Bs alias here)
  __shared__ float pT[64 * PT_LDS];       // 17.4 KB step P slice
  __shared__ f16 hS2[64 * 16];            // 2 KB outgoing h
  __shared__ unsigned tileS;
  const int tid = threadIdx.x;
  const int lane = tid & 63;
  const int w = tid >> 6;

  if (blockIdx.x >= NBLK) {
    // ---- phase 1: convert fc_w -> w16 (coherent 8B stores) ----
    const int g0 = (blockIdx.x - NBLK) * 256 + tid;
    for (int i = g0; i < 4096000; i += (NBLK_TOT - NBLK) * 256) {
      const float4 v = ((const float4*)fcw)[i];
      f16x4 r;
      r.x = (f16)v.x; r.y = (f16)v.y; r.z = (f16)v.z; r.w = (f16)v.w;
      store_h4_coh(w16 + (size_t)i * 4, r);
    }
    asm volatile("s_waitcnt vmcnt(0)" ::: "memory");
    __syncthreads();
    if (tid == 0)
      __hip_atomic_fetch_add(convDone, 1u, __ATOMIC_RELAXED,
                             __HIP_MEMORY_SCOPE_AGENT);
  } else {
    // ---- phase 1: persistent LSTM (as r14) ----
    const int u0 = blockIdx.x * 16;
    const int fr = lane & 15;
    const int fq = lane >> 4;
    const int q = fr >> 2;
    const int jw = fr & 3;
    const int grow = q * 512 + u0 + w * 4 + jw;

    f16x8 bW[16];
    {
      const f16* brow = Whh + (size_t)grow * 512;
#pragma unroll
      for (int kk = 0; kk < 16; ++kk)
        bW[kk] = *(const f16x8*)&brow[kk * 32 + fq * 8];
    }
    for (int i = tid; i < 64 * 16; i += 256) {
      const int rr = i >> 4;
      const int q4 = i & 15;
      const int g = rr >> 4, ul = rr & 15;
      const float4 v =
          *(const float4*)&PT[((size_t)(g * 512 + u0 + ul)) * 64 + q4 * 4];
      *(float4*)&pT[rr * PT_LDS + q4 * 4] = v;
    }

    float cr[4] = {0.f, 0.f, 0.f, 0.f};

    for (int t = 0; t <= T_DIM; ++t) {
      if (t > 0) {
        const f16* src = hsT + (size_t)(t - 1) * (64 * 512)
                             + (size_t)(w * 16) * 512;
        f16x8 hrow[16];
#pragma unroll
        for (int j = 0; j < 16; ++j)
          hrow[j] = load_h8_coh(src + (size_t)j * 512 + lane * 8);
#pragma unroll
        for (int j = 0; j < 16; ++j)
          *(f16x8*)&hS[(w * 16 + j) * HS_STR + lane * 8] = hrow[j];
      }
      __syncthreads();

      f32x4 acc[4];
#pragma unroll
      for (int mi = 0; mi < 4; ++mi) {
        f32x4 z = {0.f, 0.f, 0.f, 0.f};
        acc[mi] = z;
      }
      if (t > 0) {
#pragma unroll
        for (int mi = 0; mi < 4; ++mi) {
          f16x8 a[16];
#pragma unroll
          for (int kk = 0; kk < 16; ++kk)
            a[kk] =
                *(const f16x8*)&hS[(mi * 16 + fr) * HS_STR + kk * 32 + fq * 8];
#pragma unroll
          for (int kk = 0; kk < 16; ++kk)
            acc[mi] = __builtin_amdgcn_mfma_f32_16x16x32_f16(a[kk], bW[kk],
                                                             acc[mi], 0, 0, 0);
        }
      }
      const int prow = (q * 16 + w * 4 + jw) * PT_LDS;
#pragma unroll
      for (int mi = 0; mi < 4; ++mi)
#pragma unroll
        for (int r = 0; r < 4; ++r)
          acc[mi][r] += pT[prow + mi * 16 + fq * 4 + r];

#pragma unroll
      for (int r = 0; r < 4; ++r) {
        const float y0 = acc[0][r], y1 = acc[1][r], y2 = acc[2][r],
                    y3 = acc[3][r];
        const float f0 = __shfl_xor(y0, 4),  f1 = __shfl_xor(y1, 4),
                    f2 = __shfl_xor(y2, 4),  f3 = __shfl_xor(y3, 4);
        const float g0 = __shfl_xor(y0, 8),  g1 = __shfl_xor(y1, 8),
                    g2 = __shfl_xor(y2, 8),  g3 = __shfl_xor(y3, 8);
        const float o0 = __shfl_xor(y0, 12), o1 = __shfl_xor(y1, 12),
                    o2 = __shfl_xor(y2, 12), o3 = __shfl_xor(y3, 12);
        const float x  = q == 0 ? y0 : q == 1 ? y1 : q == 2 ? y2 : y3;
        const float xf = q == 0 ? f0 : q == 1 ? f1 : q == 2 ? f2 : f3;
        const float xg = q == 0 ? g0 : q == 1 ? g1 : q == 2 ? g2 : g3;
        const float xo = q == 0 ? o0 : q == 1 ? o1 : q == 2 ? o2 : o3;
        const float gi = q == 0 ? x  : q == 1 ? xf : q == 2 ? xg : xo;
        const float gf = q == 0 ? xf : q == 1 ? x  : q == 2 ? xo : xg;
        const float gg = q == 0 ? xg : q == 1 ? xo : q == 2 ? x  : xf;
        const float go = q == 0 ? xo : q == 1 ? xg : q == 2 ? xf : x;
        const float si = sigmoidf_(gi);
        const float sf = sigmoidf_(gf);
        const float tg = tanhf(gg);
        const float so = sigmoidf_(go);
        const float cn = sf * cr[r] + si * tg;
        cr[r] = cn;
        const float hn = so * tanhf(cn);
        const int b = q * 16 + fq * 4 + r;
        hS2[b * 16 + w * 4 + jw] = (f16)hn;
      }
      __syncthreads();
      {
        f16* slab = hsT + (size_t)t * (64 * 512);
        const int row = tid >> 2;
        const int c4 = tid & 3;
        const f16x4 v = *(const f16x4*)&hS2[row * 16 + c4 * 4];
        store_h4_coh(slab + (size_t)row * 512 + u0 + c4 * 4, v);
      }

      if (t < T_DIM) {
        for (int i = tid; i < 64 * 16; i += 256) {
          const int rr = i >> 4;
          const int q4 = i & 15;
          const int g = rr >> 4, ul = rr & 15;
          const float4 v = *(const float4*)
              &PT[((size_t)(t + 1) * 2048 + g * 512 + u0 + ul) * 64 + q4 * 4];
          *(float4*)&pT[rr * PT_LDS + q4 * 4] = v;
        }
        asm volatile("s_waitcnt vmcnt(0)" ::: "memory");
        __syncthreads();
        if (tid == 0)
          __hip_atomic_store(&flags[blockIdx.x * 16], (unsigned)(t + 1),
                             __ATOMIC_RELAXED, __HIP_MEMORY_SCOPE_AGENT);
        if (tid < NBLK) {
          while (__hip_atomic_load(&flags[tid * 16], __ATOMIC_RELAXED,
                                   __HIP_MEMORY_SCOPE_AGENT) <
                 (unsigned)(t + 1))
            __builtin_amdgcn_s_sleep(3);
        }
        __syncthreads();
      }
    }
    // final publication: slab 20 visible
    asm volatile("s_waitcnt vmcnt(0)" ::: "memory");
    __syncthreads();
    if (tid == 0)
      __hip_atomic_store(&flags[blockIdx.x * 16], (unsigned)(T_DIM + 1),
                         __ATOMIC_RELAXED, __HIP_MEMORY_SCOPE_AGENT);
  }

  if (!do_fc) return;

  // ---- phase 2 (all blocks): FC tiles from dynamic queue ----
  // gate on convert completion (w16 fully written)
  if (tid == 0) {
    while (__hip_atomic_load(convDone, __ATOMIC_RELAXED,
                             __HIP_MEMORY_SCOPE_AGENT) <
           (unsigned)(NBLK_TOT - NBLK))
      __builtin_amdgcn_s_sleep(3);
  }
  __syncthreads();

  const f16* Afc = hsT + (size_t)B_DIM * H_DIM;   // slabs 1..20
  f16* As = hS;                                   // [128][64]
  f16* Bs = hS + 128 * 64;
  const int lr = lane & 15;
  const int lkb = (lane >> 4) * 8;
  const int wm = (w >> 1) * 64;
  const int wn = (w & 1) * 64;

  for (;;) {
    if (tid == 0)
      tileS = __hip_atomic_fetch_add(queue, 1u, __ATOMIC_RELAXED,
                                     __HIP_MEMORY_SCOPE_AGENT);
    __syncthreads();
    const unsigned tile = tileS;
    __syncthreads();
    if (tile >= (unsigned)N_TILES) break;
    const int mt = (int)tile / 250;
    const int nt = (int)tile % 250;
    const int m0 = mt * 128;
    const int n0 = nt * 128;

    // wait for the two hsT slabs this m-tile needs (flags >= 3+2mt)
    if (tid < NBLK) {
      const unsigned need = (unsigned)(3 + 2 * mt);
      while (__hip_atomic_load(&flags[tid * 16], __ATOMIC_RELAXED,
                               __HIP_MEMORY_SCOPE_AGENT) < need)
        __builtin_amdgcn_s_sleep(3);
    }
    __syncthreads();

    f32x4 acc[4][4];
#pragma unroll
    for (int i = 0; i < 4; ++i)
#pragma unroll
      for (int j = 0; j < 4; ++j) {
        f32x4 z = {0.f, 0.f, 0.f, 0.f};
        acc[i][j] = z;
      }

    for (int kt = 0; kt < 512; kt += 64) {
      // A tile: 128 rows x 64 cols, coherent loads (hsT write-once)
      for (int i = tid; i < 1024; i += 256) {
        const int row = i >> 3;
        const int ch = i & 7;
        const f16x8 v =
            load_h8_coh(Afc + (size_t)(m0 + row) * 512 + kt + ch * 8);
        *(f16x8*)&As[row * 64 + ch * 8] = v;
      }
      // B tile via global_load_lds (w16 is LLC-fresh: coherent-stored)
#pragma unroll
      for (int i = 0; i < 4; ++i) {
        const int off = i * 4096 + w * 1024 + lane * 16;
        const int row = off >> 7;
        const int colh = (off & 127) >> 1;
        async_lds16((char*)Bs + i * 4096 + w * 1024,
                    w16 + (size_t)(n0 + row) * 512 + kt + colh);
      }
      __syncthreads();
#pragma unroll
      for (int ks = 0; ks < 2; ++ks) {
        f16x8 af[4], bf[4];
#pragma unroll
        for (int mi = 0; mi < 4; ++mi)
          af[mi] =
              *(const f16x8*)&As[(wm + mi * 16 + lr) * 64 + ks * 32 + lkb];
#pragma unroll
        for (int ni = 0; ni < 4; ++ni)
          bf[ni] =
              *(const f16x8*)&Bs[(wn + ni * 16 + lr) * 64 + ks * 32 + lkb];
#pragma unroll
        for (int mi = 0; mi < 4; ++mi)
#pragma unroll
          for (int ni = 0; ni < 4; ++ni)
            acc[mi][ni] = __builtin_amdgcn_mfma_f32_16x16x32_f16(
                af[mi], bf[ni], acc[mi][ni], 0, 0, 0);
      }
      __syncthreads();
    }

#pragma unroll
    for (int mi = 0; mi < 4; ++mi) {
      const int mbase = m0 + wm + mi * 16 + (lane >> 4) * 4;
#pragma unroll
      for (int ni = 0; ni < 4; ++ni) {
        const int n = n0 + wn + ni * 16 + lr;
        const float bv = fcb[n];
#pragma unroll
        for (int r = 0; r < 4; ++r) {
          const int mr = mbase + r;
          const int orow = (mr & 63) * 20 + (mr >> 6);
          logits16[(size_t)orow * 32000 + n] = (f16)(acc[mi][ni][r] + bv);
        }
      }
    }
  }
}

// ---------------------------------------------------------------------------
// Softmax over V=32000, row in registers (1024 thr).
// ---------------------------------------------------------------------------
__device__ __forceinline__ float waveMax(float v) {
#pragma unroll
  for (int o = 32; o > 0; o >>= 1) v = fmaxf(v, __shfl_down(v, o));
  return v;
}
__device__ __forceinline__ float waveSum(float v) {
#pragma unroll
  for (int o = 32; o > 0; o >>= 1) v += __shfl_down(v, o);
  return v;
}

__global__ __launch_bounds__(1024) void softmax_f16_kernel(
    const f16* __restrict__ lg, float* __restrict__ out) {
  const f16x8* L = (const f16x8*)(lg + (size_t)blockIdx.x * V_DIM);
  float4* p4 = (float4*)(out + (size_t)blockIdx.x * V_DIM);
  const int t = threadIdx.x;
  __shared__ float sred[16];

  float4 v[8];
  float m = -1e30f;
#pragma unroll
  for (int j = 0; j < 4; ++j) {
    const int i = j * 1024 + t;
    if (i < 4000) {
      const f16x8 h = L[i];
      v[2 * j].x     = (float)h[0]; v[2 * j].y     = (float)h[1];
      v[2 * j].z     = (float)h[2]; v[2 * j].w     = (float)h[3];
      v[2 * j + 1].x = (float)h[4]; v[2 * j + 1].y = (float)h[5];
      v[2 * j + 1].z = (float)h[6]; v[2 * j + 1].w = (float)h[7];
      m = fmaxf(m, fmaxf(fmaxf(v[2 * j].x, v[2 * j].y),
                         fmaxf(v[2 * j].z, v[2 * j].w)));
      m = fmaxf(m, fmaxf(fmaxf(v[2 * j + 1].x, v[2 * j + 1].y),
                         fmaxf(v[2 * j + 1].z, v[2 * j + 1].w)));
    }
  }
  m = waveMax(m);
  if ((t & 63) == 0) sred[t >> 6] = m;
  __syncthreads();
  float mb = sred[0];
#pragma unroll
  for (int k = 1; k < 16; ++k) mb = fmaxf(mb, sred[k]);
  __syncthreads();

  float s = 0.f;
#pragma unroll
  for (int j = 0; j < 8; ++j) {
    const int i = (j >> 1) * 1024 + t;
    if (i < 4000) {
      v[j].x = expf(v[j].x - mb);
      v[j].y = expf(v[j].y - mb);
      v[j].z = expf(v[j].z - mb);
      v[j].w = expf(v[j].w - mb);
      s += v[j].x + v[j].y + v[j].z + v[j].w;
    }
  }
  s = waveSum(s);
  if ((t & 63) == 0) sred[t >> 6] = s;
  __syncthreads();
  float sb = sred[0];
#pragma unroll
  for (int k = 1; k < 16; ++k) sb += sred[k];
  const float inv = 1.0f / sb;

#pragma unroll
  for (int j = 0; j < 4; ++j) {
    const int i = j * 1024 + t;
    if (i < 4000) {
      float4 a = v[2 * j], b = v[2 * j + 1];
      a.x *= inv; a.y *= inv; a.z *= inv; a.w *= inv;
      b.x *= inv; b.y *= inv; b.z *= inv; b.w *= inv;
      p4[2 * i] = a;
      p4[2 * i + 1] = b;
    }
  }
}

__global__ __launch_bounds__(1024) void softmax_reg_kernel(
    float* __restrict__ out) {
  float4* p4 = (float4*)(out + (size_t)blockIdx.x * V_DIM);
  const int t = threadIdx.x;
  __shared__ float sred[16];
  float4 v[8];
  float m = -1e30f;
#pragma unroll
  for (int j = 0; j < 8; ++j) {
    const int i = j * 1024 + t;
    if (i < 8000) {
      v[j] = p4[i];
      m = fmaxf(m, fmaxf(fmaxf(v[j].x, v[j].y), fmaxf(v[j].z, v[j].w)));
    }
  }
  m = waveMax(m);
  if ((t & 63) == 0) sred[t >> 6] = m;
  __syncthreads();
  float mb = sred[0];
#pragma unroll
  for (int k = 1; k < 16; ++k) mb = fmaxf(mb, sred[k]);
  __syncthreads();
  float s = 0.f;
#pragma unroll
  for (int j = 0; j < 8; ++j) {
    const int i = j * 1024 + t;
    if (i < 8000) {
      v[j].x = expf(v[j].x - mb);
      v[j].y = expf(v[j].y - mb);
      v[j].z = expf(v[j].z - mb);
      v[j].w = expf(v[j].w - mb);
      s += v[j].x + v[j].y + v[j].z + v[j].w;
    }
  }
  s = waveSum(s);
  if ((t & 63) == 0) sred[t >> 6] = s;
  __syncthreads();
  float sb = sred[0];
#pragma unroll
  for (int k = 1; k < 16; ++k) sb += sred[k];
  const float inv = 1.0f / sb;
#pragma unroll
  for (int j = 0; j < 8; ++j) {
    const int i = j * 1024 + t;
    if (i < 8000) {
      float4 o;
      o.x = v[j].x * inv; o.y = v[j].y * inv;
      o.z = v[j].z * inv; o.w = v[j].w * inv;
      p4[i] = o;
    }
  }
}

// ---------------------------------------------------------------------------
extern "C" void kernel_launch(void* const* d_in, const int* in_sizes, int n_in,
                              void* d_out, int out_size, void* d_ws, size_t ws_size,
                              hipStream_t stream) {
  const float* features = (const float*)d_in[0];
  const int*   captions = (const int*)d_in[1];
  const float* emb      = (const float*)d_in[3];
  const float* w_ih     = (const float*)d_in[4];
  const float* w_hh     = (const float*)d_in[5];
  const float* b_ih     = (const float*)d_in[6];
  const float* b_hh     = (const float*)d_in[7];
  const float* fc_w     = (const float*)d_in[8];
  const float* fc_b     = (const float*)d_in[9];
  float* out = (float*)d_out;

  // ---- d_ws layout ----
  char* ws = (char*)d_ws;
  unsigned* flags = (unsigned*)ws; ws += 4096;  // 32x64B flags + counters
  unsigned* convDone = flags + 512;             // byte 2048
  unsigned* queue    = flags + 528;             // byte 2112
  f16* hsT = (f16*)ws;  ws += (size_t)21 * B_DIM * H_DIM * 2;     // 1.38 MB
  f16* w16 = (f16*)ws;  ws += (size_t)V_DIM * H_DIM * 2;          // 32.77 MB
  f16* logits16 = (f16*)ws;  // 81.92 MB if available
  const size_t ws_need_f16logits =
      ((char*)logits16 - (char*)d_ws) + (size_t)1280 * V_DIM * 2;  // ~116 MB
  const bool use_f16_logits = ws_size >= ws_need_f16logits;

  // ---- transient scratch in d_out (dead before final output writes) ----
  float* PT    = out;                          // [21][2048][64] f32, 11 MB
  f16*   x16   = (f16*)(out + 3000000);        // [1408][512] f16
  f16*   wih16 = (f16*)(out + 3400000);        // [2048][512] f16
  f16*   whh16 = (f16*)(out + 4000000);        // [2048][512] f16
  float* bsum  = out + 4600000;                // [2048] f32

  hipMemsetAsync(flags, 0, 4096, stream);

  gather_x16_kernel<<<1408, 128, 0, stream>>>(features, captions, emb, x16);
  convert_w_kernel<<<1024, 256, 0, stream>>>(w_ih, wih16);
  convert_w_kernel<<<1024, 256, 0, stream>>>(w_hh, whh16);
  bias_sum_kernel<<<8, 256, 0, stream>>>(b_ih, b_hh, bsum);

  // proj -> P_T[t][gate-row][b]  (mode 2 epilogue)
  gemm16_kernel<<<dim3(16, 11), 256, 0, stream>>>(x16, wih16, bsum, PT, 0, 2);

  // mega: LSTM + convert + (optionally) flag-gated FC into logits16
  mega_kernel<<<NBLK_TOT, 256, 0, stream>>>(PT, whh16, hsT, flags, fc_w, w16,
                                            fc_b, logits16, convDone, queue,
                                            use_f16_logits ? 1 : 0);

  if (use_f16_logits) {
    softmax_f16_kernel<<<1280, 1024, 0, stream>>>(logits16, out);
  } else {
    const f16* Afc = hsT + (size_t)B_DIM * H_DIM;
    gemm16_kernel<<<dim3(250, 10), 256, 0, stream>>>(Afc, w16, fc_b, out,
                                                     32000, 1);
    softmax_reg_kernel<<<1280, 1024, 0, stream>>>(out);
  }
}

// Round 17
// 303.375 us; speedup vs baseline: 1.2264x; 1.2264x over previous
//
#include <hip/hip_runtime.h>
#include <cstdint>
#include <cstddef>

#define E_DIM 512
#define H_DIM 512
#define V_DIM 32000
#define B_DIM 64
#define T_DIM 20
#define NBLK 32        // LSTM blocks (16 units each); blocks 32.. do convert
#define NBLK_TOT 256
#define PT_LDS 68      // pT row stride (f32)
#define HS_STR 532     // hS row stride (f16): 266 dw == 10 mod 32 -> 2-way

typedef _Float16 f16;
typedef _Float16 f16x8 __attribute__((ext_vector_type(8)));
typedef _Float16 f16x4 __attribute__((ext_vector_type(4)));
typedef float    f32x4 __attribute__((ext_vector_type(4)));

__device__ __forceinline__ void async_lds16(void* lds, const void* g) {
  __builtin_amdgcn_global_load_lds(
      (const __attribute__((address_space(1))) uint32_t*)g,
      (__attribute__((address_space(3))) uint32_t*)lds, 16, 0, 0);
}

__device__ __forceinline__ float sigmoidf_(float x) {
  return 1.0f / (1.0f + expf(-x));
}

// Agent-coherent (cross-XCD) accesses — bypass non-coherent per-XCD L2s.
__device__ __forceinline__ f16x8 load_h8_coh(const f16* p) {
  union { unsigned long long u[2]; f16x8 v; } r;
  r.u[0] = __hip_atomic_load((const unsigned long long*)p,
                             __ATOMIC_RELAXED, __HIP_MEMORY_SCOPE_AGENT);
  r.u[1] = __hip_atomic_load((const unsigned long long*)(p + 4),
                             __ATOMIC_RELAXED, __HIP_MEMORY_SCOPE_AGENT);
  return r.v;
}
__device__ __forceinline__ void store_h4_coh(f16* p, f16x4 v) {
  union { f16x4 h; unsigned long long u; } cvt;
  cvt.h = v;
  __hip_atomic_store((unsigned long long*)p, cvt.u,
                     __ATOMIC_RELAXED, __HIP_MEMORY_SCOPE_AGENT);
}

// ---------------------------------------------------------------------------
// Fused preamble (replaces 4 small launches):
//  blocks 0..703    : gather x16 (t-major, 2 rows/block)
//  blocks 704..1727 : w_ih AND w_hh f32->f16 (one float4 index each)
//  blocks 1728..1735: bsum = b_ih + b_hh
// ---------------------------------------------------------------------------
__global__ __launch_bounds__(256) void preamble_kernel(
    const float* __restrict__ features, const int* __restrict__ captions,
    const float* __restrict__ emb, f16* __restrict__ x16,
    const float* __restrict__ w_ih, const float* __restrict__ w_hh,
    f16* __restrict__ wih16, f16* __restrict__ whh16,
    const float* __restrict__ b_ih, const float* __restrict__ b_hh,
    float* __restrict__ bsum) {
  const int blk = blockIdx.x;
  const int tid = threadIdx.x;
  if (blk < 704) {
    const int m = blk * 2 + (tid >> 7);      // 0..1407
    const int j = tid & 127;
    f16x4 r4 = {(f16)0.f, (f16)0.f, (f16)0.f, (f16)0.f};
    if (m < 1344) {
      const int b = m & 63;
      const int t = m >> 6;
      const float* src = (t == 0)
          ? features + (size_t)b * E_DIM
          : emb + (size_t)captions[b * T_DIM + (t - 1)] * E_DIM;
      const float4 v = ((const float4*)src)[j];
      r4.x = (f16)v.x; r4.y = (f16)v.y; r4.z = (f16)v.z; r4.w = (f16)v.w;
    }
    ((f16x4*)(x16 + (size_t)m * 512))[j] = r4;
  } else if (blk < 1728) {
    const int i = (blk - 704) * 256 + tid;   // 0..262143 (float4 index)
    const float4 v1 = ((const float4*)w_ih)[i];
    f16x4 r1;
    r1.x = (f16)v1.x; r1.y = (f16)v1.y; r1.z = (f16)v1.z; r1.w = (f16)v1.w;
    ((f16x4*)wih16)[i] = r1;
    const float4 v2 = ((const float4*)w_hh)[i];
    f16x4 r2;
    r2.x = (f16)v2.x; r2.y = (f16)v2.y; r2.z = (f16)v2.z; r2.w = (f16)v2.w;
    ((f16x4*)whh16)[i] = r2;
  } else {
    const int i = (blk - 1728) * 256 + tid;
    if (i < 2048) bsum[i] = b_ih[i] + b_hh[i];
  }
}

// ---------------------------------------------------------------------------
// K=512 fp16 GEMM (B^T form). mode 0: plain; mode 1: FC row-remap;
// mode 2: proj P_T write off = (m>>6)*131072 + n*64 + (m&63).
// ---------------------------------------------------------------------------
__global__ __launch_bounds__(256) void gemm16_kernel(
    const f16* __restrict__ A, const f16* __restrict__ Bw,
    const float* __restrict__ bias, float* __restrict__ C, int ldc,
    int mode) {
  __shared__ f16 As[128 * 64];
  __shared__ f16 Bs[128 * 64];
  const int tid = threadIdx.x;
  const int lane = tid & 63;
  const int wid = tid >> 6;
  const int m0 = blockIdx.y * 128;
  const int n0 = blockIdx.x * 128;
  const int wm = (wid >> 1) * 64;
  const int wn = (wid & 1) * 64;

  f32x4 acc[4][4];
#pragma unroll
  for (int i = 0; i < 4; ++i)
#pragma unroll
    for (int j = 0; j < 4; ++j) {
      f32x4 z = {0.f, 0.f, 0.f, 0.f};
      acc[i][j] = z;
    }
  const int lr = lane & 15;
  const int lkb = (lane >> 4) * 8;

  for (int kt = 0; kt < 512; kt += 64) {
#pragma unroll
    for (int i = 0; i < 4; ++i) {
      const int off = i * 4096 + wid * 1024 + lane * 16;
      const int row = off >> 7;
      const int colh = (off & 127) >> 1;
      async_lds16((char*)As + i * 4096 + wid * 1024,
                  A + (size_t)(m0 + row) * 512 + kt + colh);
      async_lds16((char*)Bs + i * 4096 + wid * 1024,
                  Bw + (size_t)(n0 + row) * 512 + kt + colh);
    }
    __syncthreads();
#pragma unroll
    for (int ks = 0; ks < 2; ++ks) {
      f16x8 af[4], bf[4];
#pragma unroll
      for (int mi = 0; mi < 4; ++mi)
        af[mi] = *(const f16x8*)&As[(wm + mi * 16 + lr) * 64 + ks * 32 + lkb];
#pragma unroll
      for (int ni = 0; ni < 4; ++ni)
        bf[ni] = *(const f16x8*)&Bs[(wn + ni * 16 + lr) * 64 + ks * 32 + lkb];
#pragma unroll
      for (int mi = 0; mi < 4; ++mi)
#pragma unroll
        for (int ni = 0; ni < 4; ++ni)
          acc[mi][ni] = __builtin_amdgcn_mfma_f32_16x16x32_f16(
              af[mi], bf[ni], acc[mi][ni], 0, 0, 0);
    }
    __syncthreads();
  }

#pragma unroll
  for (int mi = 0; mi < 4; ++mi) {
    const int mbase = m0 + wm + mi * 16 + (lane >> 4) * 4;
#pragma unroll
    for (int ni = 0; ni < 4; ++ni) {
      const int n = n0 + wn + ni * 16 + lr;
      const float bv = bias[n];
#pragma unroll
      for (int r = 0; r < 4; ++r) {
        const int mr = mbase + r;
        size_t off;
        if (mode == 2)
          off = (size_t)(mr >> 6) * (2048 * 64) + (size_t)n * 64 + (mr & 63);
        else if (mode == 1)
          off = (size_t)((mr & 63) * 20 + (mr >> 6)) * ldc + n;
        else
          off = (size_t)mr * ldc + n;
        C[off] = acc[mi][ni][r] + bv;
      }
    }
  }
}

// Same GEMM, f16 C output, FC-only (ldc=32000, rows remapped to b-major).
__global__ __launch_bounds__(256) void gemm16_f16out_kernel(
    const f16* __restrict__ A, const f16* __restrict__ Bw,
    const float* __restrict__ bias, f16* __restrict__ C16) {
  __shared__ f16 As[128 * 64];
  __shared__ f16 Bs[128 * 64];
  const int tid = threadIdx.x;
  const int lane = tid & 63;
  const int wid = tid >> 6;
  const int m0 = blockIdx.y * 128;
  const int n0 = blockIdx.x * 128;
  const int wm = (wid >> 1) * 64;
  const int wn = (wid & 1) * 64;

  f32x4 acc[4][4];
#pragma unroll
  for (int i = 0; i < 4; ++i)
#pragma unroll
    for (int j = 0; j < 4; ++j) {
      f32x4 z = {0.f, 0.f, 0.f, 0.f};
      acc[i][j] = z;
    }
  const int lr = lane & 15;
  const int lkb = (lane >> 4) * 8;

  for (int kt = 0; kt < 512; kt += 64) {
#pragma unroll
    for (int i = 0; i < 4; ++i) {
      const int off = i * 4096 + wid * 1024 + lane * 16;
      const int row = off >> 7;
      const int colh = (off & 127) >> 1;
      async_lds16((char*)As + i * 4096 + wid * 1024,
                  A + (size_t)(m0 + row) * 512 + kt + colh);
      async_lds16((char*)Bs + i * 4096 + wid * 1024,
                  Bw + (size_t)(n0 + row) * 512 + kt + colh);
    }
    __syncthreads();
#pragma unroll
    for (int ks = 0; ks < 2; ++ks) {
      f16x8 af[4], bf[4];
#pragma unroll
      for (int mi = 0; mi < 4; ++mi)
        af[mi] = *(const f16x8*)&As[(wm + mi * 16 + lr) * 64 + ks * 32 + lkb];
#pragma unroll
      for (int ni = 0; ni < 4; ++ni)
        bf[ni] = *(const f16x8*)&Bs[(wn + ni * 16 + lr) * 64 + ks * 32 + lkb];
#pragma unroll
      for (int mi = 0; mi < 4; ++mi)
#pragma unroll
        for (int ni = 0; ni < 4; ++ni)
          acc[mi][ni] = __builtin_amdgcn_mfma_f32_16x16x32_f16(
              af[mi], bf[ni], acc[mi][ni], 0, 0, 0);
    }
    __syncthreads();
  }

#pragma unroll
  for (int mi = 0; mi < 4; ++mi) {
    const int mbase = m0 + wm + mi * 16 + (lane >> 4) * 4;
#pragma unroll
    for (int ni = 0; ni < 4; ++ni) {
      const int n = n0 + wn + ni * 16 + lr;
      const float bv = bias[n];
#pragma unroll
      for (int r = 0; r < 4; ++r) {
        const int mr = mbase + r;
        const int orow = (mr & 63) * 20 + (mr >> 6);
        C16[(size_t)orow * 32000 + n] = (f16)(acc[mi][ni][r] + bv);
      }
    }
  }
}

// ---------------------------------------------------------------------------
// Persistent LSTM (fused): blocks 0..31 run the 21-step LSTM (hS stride 532
// -> 2-way bank aliasing); blocks 32..255 run the fc_w f32->f16 convert on
// otherwise-idle CUs. 256 blocks x 87.5KB LDS = 1 block/CU, co-resident.
// ---------------------------------------------------------------------------
__global__ __launch_bounds__(256, 1) void lstm_persistent7(
    const float* __restrict__ PT, const f16* __restrict__ Whh,
    f16* __restrict__ hsT, unsigned* __restrict__ flags,
    const float* __restrict__ fcw, f16* __restrict__ w16) {
  __shared__ f16 hS[64 * HS_STR];         // 68.1 KB staged h
  __shared__ float pT[64 * PT_LDS];       // 17.4 KB step P slice
  __shared__ f16 hS2[64 * 16];            // 2 KB outgoing h
  const int tid = threadIdx.x;

  if (blockIdx.x >= NBLK) {
    // ---- convert lane: w16 = (f16)fc_w, grid-stride over 4.096M float4 ----
    const int g0 = (blockIdx.x - NBLK) * 256 + tid;
    for (int i = g0; i < 4096000; i += (NBLK_TOT - NBLK) * 256) {
      const float4 v = ((const float4*)fcw)[i];
      f16x4 r;
      r.x = (f16)v.x; r.y = (f16)v.y; r.z = (f16)v.z; r.w = (f16)v.w;
      ((f16x4*)w16)[i] = r;
    }
    return;
  }

  const int lane = tid & 63;
  const int w = tid >> 6;
  const int u0 = blockIdx.x * 16;
  const int fr = lane & 15;
  const int fq = lane >> 4;
  const int q = fr >> 2;                  // lane's gate / b-tile
  const int jw = fr & 3;                  // unit within wave
  const int grow = q * 512 + u0 + w * 4 + jw;

  // W fragments -> VGPRs once (scatter paid once, reused 20 steps)
  f16x8 bW[16];
  {
    const f16* brow = Whh + (size_t)grow * 512;
#pragma unroll
    for (int kk = 0; kk < 16; ++kk)
      bW[kk] = *(const f16x8*)&brow[kk * 32 + fq * 8];
  }

  // prologue: stage P slice for t=0 (coalesced 256B rows from L2)
  for (int i = tid; i < 64 * 16; i += 256) {
    const int rr = i >> 4;                // block gate row: g*16 + ul
    const int q4 = i & 15;
    const int g = rr >> 4, ul = rr & 15;
    const float4 v =
        *(const float4*)&PT[((size_t)(g * 512 + u0 + ul)) * 64 + q4 * 4];
    *(float4*)&pT[rr * PT_LDS + q4 * 4] = v;
  }

  float cr[4] = {0.f, 0.f, 0.f, 0.f};  // c[b=q*16+fq*4+r][u0+w*4+jw]

  for (int t = 0; t <= T_DIM; ++t) {
    if (t > 0) {
      // stage h: wave w loads rows w*16..+15 (contiguous, lane-coalesced)
      const f16* src = hsT + (size_t)(t - 1) * (64 * 512)
                           + (size_t)(w * 16) * 512;
      f16x8 hrow[16];
#pragma unroll
      for (int j = 0; j < 16; ++j)
        hrow[j] = load_h8_coh(src + (size_t)j * 512 + lane * 8);
#pragma unroll
      for (int j = 0; j < 16; ++j)
        *(f16x8*)&hS[(w * 16 + j) * HS_STR + lane * 8] = hrow[j];
    }
    __syncthreads();   // publishes hS (and pT from prefetch/prologue)

    f32x4 acc[4];
#pragma unroll
    for (int mi = 0; mi < 4; ++mi) {
      f32x4 z = {0.f, 0.f, 0.f, 0.f};
      acc[mi] = z;
    }
    if (t > 0) {
#pragma unroll
      for (int mi = 0; mi < 4; ++mi) {
        f16x8 a[16];
#pragma unroll
        for (int kk = 0; kk < 16; ++kk)
          a[kk] =
              *(const f16x8*)&hS[(mi * 16 + fr) * HS_STR + kk * 32 + fq * 8];
#pragma unroll
        for (int kk = 0; kk < 16; ++kk)
          acc[mi] = __builtin_amdgcn_mfma_f32_16x16x32_f16(a[kk], bW[kk],
                                                           acc[mi], 0, 0, 0);
      }
    }
    // P-add: lane's gate row rr_b = q*16 + w*4 + jw
    const int prow = (q * 16 + w * 4 + jw) * PT_LDS;
#pragma unroll
    for (int mi = 0; mi < 4; ++mi)
#pragma unroll
      for (int r = 0; r < 4; ++r)
        acc[mi][r] += pT[prow + mi * 16 + fq * 4 + r];

    // elementwise, all 64 lanes: lane processes tile mi == q
#pragma unroll
    for (int r = 0; r < 4; ++r) {
      const float y0 = acc[0][r], y1 = acc[1][r], y2 = acc[2][r],
                  y3 = acc[3][r];
      const float f0 = __shfl_xor(y0, 4),  f1 = __shfl_xor(y1, 4),
                  f2 = __shfl_xor(y2, 4),  f3 = __shfl_xor(y3, 4);
      const float g0 = __shfl_xor(y0, 8),  g1 = __shfl_xor(y1, 8),
                  g2 = __shfl_xor(y2, 8),  g3 = __shfl_xor(y3, 8);
      const float o0 = __shfl_xor(y0, 12), o1 = __shfl_xor(y1, 12),
                  o2 = __shfl_xor(y2, 12), o3 = __shfl_xor(y3, 12);
      const float x  = q == 0 ? y0 : q == 1 ? y1 : q == 2 ? y2 : y3;
      const float xf = q == 0 ? f0 : q == 1 ? f1 : q == 2 ? f2 : f3;
      const float xg = q == 0 ? g0 : q == 1 ? g1 : q == 2 ? g2 : g3;
      const float xo = q == 0 ? o0 : q == 1 ? o1 : q == 2 ? o2 : o3;
      // gate permutation by q (x = own gate q; partners at q^1,q^2,q^3)
      const float gi = q == 0 ? x  : q == 1 ? xf : q == 2 ? xg : xo;
      const float gf = q == 0 ? xf : q == 1 ? x  : q == 2 ? xo : xg;
      const float gg = q == 0 ? xg : q == 1 ? xo : q == 2 ? x  : xf;
      const float go = q == 0 ? xo : q == 1 ? xg : q == 2 ? xf : x;
      const float si = sigmoidf_(gi);
      const float sf = sigmoidf_(gf);
      const float tg = tanhf(gg);
      const float so = sigmoidf_(go);
      const float cn = sf * cr[r] + si * tg;
      cr[r] = cn;
      const float hn = so * tanhf(cn);
      const int b = q * 16 + fq * 4 + r;
      hS2[b * 16 + w * 4 + jw] = (f16)hn;
    }
    __syncthreads();

    // coalesced coherent store: block's [64 b][16 u] region in 8B chunks
    {
      f16* slab = hsT + (size_t)t * (64 * 512);
      const int row = tid >> 2;
      const int c4 = tid & 3;
      const f16x4 v = *(const f16x4*)&hS2[row * 16 + c4 * 4];
      store_h4_coh(slab + (size_t)row * 512 + u0 + c4 * 4, v);
    }

    if (t < T_DIM) {
      // prefetch next step's P slice into pT (overlaps barrier wait)
      for (int i = tid; i < 64 * 16; i += 256) {
        const int rr = i >> 4;
        const int q4 = i & 15;
        const int g = rr >> 4, ul = rr & 15;
        const float4 v = *(const float4*)
            &PT[((size_t)(t + 1) * 2048 + g * 512 + u0 + ul) * 64 + q4 * 4];
        *(float4*)&pT[rr * PT_LDS + q4 * 4] = v;
      }
      asm volatile("s_waitcnt vmcnt(0)" ::: "memory");
      __syncthreads();
      if (tid == 0)
        __hip_atomic_store(&flags[blockIdx.x * 16], (unsigned)(t + 1),
                           __ATOMIC_RELAXED, __HIP_MEMORY_SCOPE_AGENT);
      if (tid < NBLK) {
        while (__hip_atomic_load(&flags[tid * 16], __ATOMIC_RELAXED,
                                 __HIP_MEMORY_SCOPE_AGENT) < (unsigned)(t + 1))
          __builtin_amdgcn_s_sleep(3);
      }
      __syncthreads();
    }
  }
}

// ---------------------------------------------------------------------------
// Softmax over V=32000, row in registers (1024 thr).
// ---------------------------------------------------------------------------
__device__ __forceinline__ float waveMax(float v) {
#pragma unroll
  for (int o = 32; o > 0; o >>= 1) v = fmaxf(v, __shfl_down(v, o));
  return v;
}
__device__ __forceinline__ float waveSum(float v) {
#pragma unroll
  for (int o = 32; o > 0; o >>= 1) v += __shfl_down(v, o);
  return v;
}

__global__ __launch_bounds__(1024) void softmax_f16_kernel(
    const f16* __restrict__ lg, float* __restrict__ out) {
  const f16x8* L = (const f16x8*)(lg + (size_t)blockIdx.x * V_DIM);
  float4* p4 = (float4*)(out + (size_t)blockIdx.x * V_DIM);
  const int t = threadIdx.x;
  __shared__ float sred[16];

  float4 v[8];
  float m = -1e30f;
#pragma unroll
  for (int j = 0; j < 4; ++j) {
    const int i = j * 1024 + t;
    if (i < 4000) {
      const f16x8 h = L[i];
      v[2 * j].x     = (float)h[0]; v[2 * j].y     = (float)h[1];
      v[2 * j].z     = (float)h[2]; v[2 * j].w     = (float)h[3];
      v[2 * j + 1].x = (float)h[4]; v[2 * j + 1].y = (float)h[5];
      v[2 * j + 1].z = (float)h[6]; v[2 * j + 1].w = (float)h[7];
      m = fmaxf(m, fmaxf(fmaxf(v[2 * j].x, v[2 * j].y),
                         fmaxf(v[2 * j].z, v[2 * j].w)));
      m = fmaxf(m, fmaxf(fmaxf(v[2 * j + 1].x, v[2 * j + 1].y),
                         fmaxf(v[2 * j + 1].z, v[2 * j + 1].w)));
    }
  }
  m = waveMax(m);
  if ((t & 63) == 0) sred[t >> 6] = m;
  __syncthreads();
  float mb = sred[0];
#pragma unroll
  for (int k = 1; k < 16; ++k) mb = fmaxf(mb, sred[k]);
  __syncthreads();

  float s = 0.f;
#pragma unroll
  for (int j = 0; j < 8; ++j) {
    const int i = (j >> 1) * 1024 + t;
    if (i < 4000) {
      v[j].x = expf(v[j].x - mb);
      v[j].y = expf(v[j].y - mb);
      v[j].z = expf(v[j].z - mb);
      v[j].w = expf(v[j].w - mb);
      s += v[j].x + v[j].y + v[j].z + v[j].w;
    }
  }
  s = waveSum(s);
  if ((t & 63) == 0) sred[t >> 6] = s;
  __syncthreads();
  float sb = sred[0];
#pragma unroll
  for (int k = 1; k < 16; ++k) sb += sred[k];
  const float inv = 1.0f / sb;

#pragma unroll
  for (int j = 0; j < 4; ++j) {
    const int i = j * 1024 + t;
    if (i < 4000) {
      float4 a = v[2 * j], b = v[2 * j + 1];
      a.x *= inv; a.y *= inv; a.z *= inv; a.w *= inv;
      b.x *= inv; b.y *= inv; b.z *= inv; b.w *= inv;
      p4[2 * i] = a;
      p4[2 * i + 1] = b;
    }
  }
}

__global__ __launch_bounds__(1024) void softmax_reg_kernel(
    float* __restrict__ out) {
  float4* p4 = (float4*)(out + (size_t)blockIdx.x * V_DIM);
  const int t = threadIdx.x;
  __shared__ float sred[16];
  float4 v[8];
  float m = -1e30f;
#pragma unroll
  for (int j = 0; j < 8; ++j) {
    const int i = j * 1024 + t;
    if (i < 8000) {
      v[j] = p4[i];
      m = fmaxf(m, fmaxf(fmaxf(v[j].x, v[j].y), fmaxf(v[j].z, v[j].w)));
    }
  }
  m = waveMax(m);
  if ((t & 63) == 0) sred[t >> 6] = m;
  __syncthreads();
  float mb = sred[0];
#pragma unroll
  for (int k = 1; k < 16; ++k) mb = fmaxf(mb, sred[k]);
  __syncthreads();
  float s = 0.f;
#pragma unroll
  for (int j = 0; j < 8; ++j) {
    const int i = j * 1024 + t;
    if (i < 8000) {
      v[j].x = expf(v[j].x - mb);
      v[j].y = expf(v[j].y - mb);
      v[j].z = expf(v[j].z - mb);
      v[j].w = expf(v[j].w - mb);
      s += v[j].x + v[j].y + v[j].z + v[j].w;
    }
  }
  s = waveSum(s);
  if ((t & 63) == 0) sred[t >> 6] = s;
  __syncthreads();
  float sb = sred[0];
#pragma unroll
  for (int k = 1; k < 16; ++k) sb += sred[k];
  const float inv = 1.0f / sb;
#pragma unroll
  for (int j = 0; j < 8; ++j) {
    const int i = j * 1024 + t;
    if (i < 8000) {
      float4 o;
      o.x = v[j].x * inv; o.y = v[j].y * inv;
      o.z = v[j].z * inv; o.w = v[j].w * inv;
      p4[i] = o;
    }
  }
}

// ---------------------------------------------------------------------------
extern "C" void kernel_launch(void* const* d_in, const int* in_sizes, int n_in,
                              void* d_out, int out_size, void* d_ws, size_t ws_size,
                              hipStream_t stream) {
  const float* features = (const float*)d_in[0];
  const int*   captions = (const int*)d_in[1];
  const float* emb      = (const float*)d_in[3];
  const float* w_ih     = (const float*)d_in[4];
  const float* w_hh     = (const float*)d_in[5];
  const float* b_ih     = (const float*)d_in[6];
  const float* b_hh     = (const float*)d_in[7];
  const float* fc_w     = (const float*)d_in[8];
  const float* fc_b     = (const float*)d_in[9];
  float* out = (float*)d_out;

  // ---- d_ws layout ----
  char* ws = (char*)d_ws;
  unsigned* flags = (unsigned*)ws; ws += 2048;                    // 32 x 64B
  f16* hsT = (f16*)ws;  ws += (size_t)21 * B_DIM * H_DIM * 2;     // 1.38 MB
  f16* w16 = (f16*)ws;  ws += (size_t)V_DIM * H_DIM * 2;          // 32.77 MB
  f16* logits16 = (f16*)ws;  // 81.92 MB if available
  const size_t ws_need_f16logits =
      ((char*)logits16 - (char*)d_ws) + (size_t)1280 * V_DIM * 2;  // ~116 MB
  const bool use_f16_logits = ws_size >= ws_need_f16logits;

  // ---- transient scratch in d_out (dead before final output writes) ----
  float* PT    = out;                          // [21][2048][64] f32, 11 MB
  f16*   x16   = (f16*)(out + 3000000);        // [1408][512] f16
  f16*   wih16 = (f16*)(out + 3400000);        // [2048][512] f16
  f16*   whh16 = (f16*)(out + 4000000);        // [2048][512] f16
  float* bsum  = out + 4600000;                // [2048] f32

  hipMemsetAsync(flags, 0, 2048, stream);

  // fused preamble: gather + w_ih/w_hh convert + bias sum (one launch)
  preamble_kernel<<<1736, 256, 0, stream>>>(features, captions, emb, x16,
                                            w_ih, w_hh, wih16, whh16,
                                            b_ih, b_hh, bsum);

  // proj -> P_T[t][gate-row][b]  (mode 2 epilogue)
  gemm16_kernel<<<dim3(16, 11), 256, 0, stream>>>(x16, wih16, bsum, PT, 0, 2);

  // fused: blocks 0..31 = 21 LSTM steps; blocks 32..255 = fc_w convert
  lstm_persistent7<<<NBLK_TOT, 256, 0, stream>>>(PT, whh16, hsT, flags,
                                                 fc_w, w16);

  // FC A = hsT slabs 1..20 (rows t-major), C rows remapped to b-major
  const f16* Afc = hsT + (size_t)B_DIM * H_DIM;
  if (use_f16_logits) {
    gemm16_f16out_kernel<<<dim3(250, 10), 256, 0, stream>>>(Afc, w16, fc_b,
                                                            logits16);
    softmax_f16_kernel<<<1280, 1024, 0, stream>>>(logits16, out);
  } else {
    gemm16_kernel<<<dim3(250, 10), 256, 0, stream>>>(Afc, w16, fc_b, out,
                                                     32000, 1);
    softmax_reg_kernel<<<1280, 1024, 0, stream>>>(out);
  }
}